// Round 6
// baseline (400.214 us; speedup 1.0000x reference)
//
#include <hip/hip_runtime.h>
#include <hip/hip_bf16.h>
#include <math.h>

#define SEQ   2048
#define EMBED 2048
#define NHEAD 16
#define DHEAD 128
#define BATCH 2

#define NX   ((size_t)BATCH * SEQ * EMBED)   // 8388608
#define NW1  ((size_t)3 * EMBED * EMBED)     // 12582912
#define NB1  ((size_t)3 * EMBED)             // 6144
#define NW2  ((size_t)EMBED * EMBED)         // 4194304
#define NB2  ((size_t)EMBED)                 // 2048

typedef __bf16 bf16;
typedef __attribute__((__ext_vector_type__(8))) __bf16 bf16x8;
typedef __attribute__((__ext_vector_type__(4))) __bf16 bf16x4;
typedef __attribute__((__ext_vector_type__(4))) float f32x4;
typedef __attribute__((__ext_vector_type__(4))) unsigned int u32x4;

#define NEG_BIG (-1.0e30f)

__device__ __forceinline__ f32x4 mfma_16x16x32(bf16x8 a, bf16x8 b, f32x4 c) {
  return __builtin_amdgcn_mfma_f32_16x16x32_bf16(a, b, c, 0, 0, 0);
}

// async global->LDS, 16B per lane; dst is wave-uniform base, lane i lands at
// dst + i*16B (m97-verified pattern)
__device__ __forceinline__ void llds16(bf16* dst, const bf16* src) {
  __builtin_amdgcn_global_load_lds(
      (const __attribute__((address_space(1))) void*)src,
      (__attribute__((address_space(3))) void*)dst, 16, 0, 0);
}

// raw barrier emitted as opaque asm: the compiler's memory legalizer cannot
// attach an s_waitcnt vmcnt(0) drain to it (T4 insurance). "memory" clobber
// still pins all LDS/global ops on either side.
#define BARRAW() asm volatile("s_barrier" ::: "memory")

// ---------------------------------------------------------------------------
// Input normalization: detect fp32 vs bf16 storage, convert to bf16 ws.
// ---------------------------------------------------------------------------
__global__ void convert_inputs(const void* __restrict__ xin,
                               const void* __restrict__ w1in,
                               const void* __restrict__ b1in,
                               const void* __restrict__ w2in,
                               const void* __restrict__ b2in,
                               bf16* __restrict__ xb, bf16* __restrict__ w1b,
                               bf16* __restrict__ b1b, bf16* __restrict__ w2b,
                               bf16* __restrict__ b2b, int* __restrict__ flagp)
{
  __shared__ int sflag;
  if (threadIdx.x == 0) sflag = 0;
  __syncthreads();
  const unsigned short* xh = (const unsigned short*)xin;
  int huge = 0;
  for (int i = threadIdx.x; i < 2048; i += 256) {
    float f = __uint_as_float((unsigned int)xh[i] << 16);
    if (!(fabsf(f) <= 1e4f)) huge = 1;  // catches NaN/Inf too
  }
  if (huge) sflag = 1;
  __syncthreads();
  const int isf32 = sflag;
  if (blockIdx.x == 0 && threadIdx.x == 0) *flagp = isf32;

  const void* srcs[5] = {xin, w1in, b1in, w2in, b2in};
  bf16* dsts[5] = {xb, w1b, b1b, w2b, b2b};
  const size_t lens[5] = {NX, NW1, NB1, NW2, NB2};
  const size_t gid = (size_t)blockIdx.x * blockDim.x + threadIdx.x;
  const size_t gstride = (size_t)gridDim.x * blockDim.x;
  for (int sidx = 0; sidx < 5; ++sidx) {
    const size_t n8 = lens[sidx] >> 3;
    bf16* d = dsts[sidx];
    if (isf32) {
      const float* s = (const float*)srcs[sidx];
      for (size_t i = gid; i < n8; i += gstride) {
        const float* sp = s + i * 8;
        bf16x8 r;
#pragma unroll
        for (int j = 0; j < 8; ++j) r[j] = (bf16)sp[j];
        *(bf16x8*)(d + i * 8) = r;
      }
    } else {
      const u32x4* s = (const u32x4*)srcs[sidx];
      for (size_t i = gid; i < n8; i += gstride)
        *(u32x4*)(d + i * 8) = s[i];
    }
  }
}

// ---------------------------------------------------------------------------
// QKV GEMM, 256x256 with register-level software pipelining.
// BM=BN=256, BK=64; 512 thr = 8 waves (2M x 4N), 128x64 out/wave.
// LDS 128KB: [buf2]{ A.ks0 | A.ks1 | B.ks0 | B.ks1 } 8K-elem regions, 64B
// rows, granule XOR (bit1 ^= row-bit3) on stage-source AND read (r4/r5
// proven: SQ_LDS_BANK_CONFLICT == 0).
// NEW (r6): A-fragments double-buffered in registers (afE/afO). Phase p
// issues the 4 B-reads it needs + the 8 A-reads for phase p+1 + one stage
// unit, then lgkmcnt(8) (drain prev-A + B, keep the 8 ahead-reads in
// flight), sched_barrier(0), 32-MFMA cluster under setprio. The MFMA
// cluster of phase p thus overlaps the LDS drain of phase p+1's A-frags --
// the CU matrix and LDS pipes co-run instead of alternating (r5: 2370
// cy/phase = MFMA 1240 + LDS 1130 back-to-back).
// Stage schedule: phase (tt,ks0) stages half (tt+1,ks1); (tt,ks1) stages
// (tt+2,ks0). vmcnt(4) every phase end + barrier = collective landing
// guarantee one full phase before first read. Race matrix verified:
// every stage write lands >=1 barrier after its region's last read drains.
// ---------------------------------------------------------------------------
__global__ __launch_bounds__(512, 1) void gemmM(
    const bf16* __restrict__ A, const bf16* __restrict__ B,
    const bf16* __restrict__ bias,
    bf16* __restrict__ outq, bf16* __restrict__ outk, bf16* __restrict__ outv)
{
  __shared__ __align__(16) bf16 lds_[65536];  // 128 KiB
  const int t = threadIdx.x;
  const int lane = t & 63, w = t >> 6;
  const int wm = w >> 2, wn = w & 3;          // 2M x 4N waves, 128x64 each
  const int lr = lane & 15, lq = lane >> 4;
  // XCD-bijective swizzle: 384 % 8 == 0, chunks of 48; by fastest
  const int f = blockIdx.x;
  const int o = (f & 7) * 48 + (f >> 3);
  const int by = o & 15, bx = o >> 4;
  const int m0 = by << 8, n0 = bx << 8;
  const int K = EMBED;
  const int NT = K >> 6;                      // 32 K-tiles

  // staging map: half (kt,ks) = A 256x32 + B 256x32 = 32KB = 4 llds16/wave.
  const int sg8 = ((lane & 3) ^ (((lane >> 5) & 1) << 1)) << 3;
  const bf16* aS  = A + (size_t)(m0 + w * 32 + (lane >> 2)) * K + sg8;
  const bf16* aS2 = aS + (size_t)16 * K;
  const bf16* bS  = B + (size_t)(n0 + w * 32 + (lane >> 2)) * K + sg8;
  const bf16* bS2 = bS + (size_t)16 * K;
  const int dA = w * 1024;          // elem offset of wave's A call-0 region
  const int dB = 16384 + w * 1024;  // elem offset of wave's B call-0 region

#define STAGE_HALF(kt_, ks_)                                                 \
  {                                                                          \
    const int _bufb = ((kt_) & 1) * 32768 + (ks_) * 8192;                    \
    const int _kc = ((kt_) << 6) + (ks_) * 32;                               \
    llds16(lds_ + _bufb + dA, aS + _kc);                                     \
    llds16(lds_ + _bufb + dA + 512, aS2 + _kc);                              \
    llds16(lds_ + _bufb + dB, bS + _kc);                                     \
    llds16(lds_ + _bufb + dB + 512, bS2 + _kc);                              \
  }

  f32x4 acc[8][4];
#pragma unroll
  for (int i = 0; i < 8; ++i)
#pragma unroll
    for (int j = 0; j < 4; ++j) acc[i][j] = (f32x4){0.f, 0.f, 0.f, 0.f};

  // fragment reads: row stride 64B; granule XOR by row-bit3 (conflict-free)
  const int rg8 = (lq ^ (((lr >> 3) & 1) << 1)) << 3;
  const int arow_ = (wm * 128 + lr) * 32 + rg8;          // + ai*512
  const int brow_ = 16384 + (wn * 64 + lr) * 32 + rg8;   // + ni*512

  bf16x8 afE[8], afO[8], bfv[4];

  // prologue: stage (0,ks0),(0,ks1),(1,ks0); ensure tile0 landed; pre-read
  // afE <- (0,ks0). SH(1,ks0) stays in flight (drained at end of (0,ks0)).
  STAGE_HALF(0, 0);
  STAGE_HALF(0, 1);
  STAGE_HALF(1, 0);
  asm volatile("s_waitcnt vmcnt(4)" ::: "memory");
  BARRAW();
#pragma unroll
  for (int ai = 0; ai < 8; ++ai)
    afE[ai] = *(const bf16x8*)(lds_ + arow_ + ai * 512);

#pragma unroll 1
  for (int tt = 0; tt < NT; ++tt) {
    const int bufb = (tt & 1) * 32768;
    const int nbufb = bufb ^ 32768;
    // ---------------- phase ks0: MFMA(afE, B.ks0); ahead-read A.ks1 -------
#pragma unroll
    for (int ni = 0; ni < 4; ++ni)
      bfv[ni] = *(const bf16x8*)(lds_ + bufb + brow_ + ni * 512);
#pragma unroll
    for (int ai = 0; ai < 8; ++ai)
      afO[ai] = *(const bf16x8*)(lds_ + bufb + 8192 + arow_ + ai * 512);
    if (tt + 1 < NT) STAGE_HALF(tt + 1, 1);
    asm volatile("s_waitcnt lgkmcnt(8)" ::: "memory");  // drain afE + bfv
    __builtin_amdgcn_sched_barrier(0);
    __builtin_amdgcn_s_setprio(1);
#pragma unroll
    for (int ai = 0; ai < 8; ++ai)
#pragma unroll
      for (int ni = 0; ni < 4; ++ni)
        acc[ai][ni] = mfma_16x16x32(afE[ai], bfv[ni], acc[ai][ni]);
    __builtin_amdgcn_s_setprio(0);
    asm volatile("s_waitcnt vmcnt(4)" ::: "memory");
    BARRAW();
    // ---------------- phase ks1: MFMA(afO, B.ks1); ahead-read (tt+1).ks0 --
#pragma unroll
    for (int ni = 0; ni < 4; ++ni)
      bfv[ni] = *(const bf16x8*)(lds_ + bufb + 8192 + brow_ + ni * 512);
    if (tt + 1 < NT) {
#pragma unroll
      for (int ai = 0; ai < 8; ++ai)
        afE[ai] = *(const bf16x8*)(lds_ + nbufb + arow_ + ai * 512);
    }
    if (tt + 2 < NT) STAGE_HALF(tt + 2, 0);
    asm volatile("s_waitcnt lgkmcnt(8)" ::: "memory");  // drain afO + bfv
    __builtin_amdgcn_sched_barrier(0);
    __builtin_amdgcn_s_setprio(1);
#pragma unroll
    for (int ai = 0; ai < 8; ++ai)
#pragma unroll
      for (int ni = 0; ni < 4; ++ni)
        acc[ai][ni] = mfma_16x16x32(afO[ai], bfv[ni], acc[ai][ni]);
    __builtin_amdgcn_s_setprio(0);
    asm volatile("s_waitcnt vmcnt(4)" ::: "memory");
    BARRAW();
  }
#undef STAGE_HALF

  // epilogue: row(M) = wm*128 + ai*16 + lq*4 + reg, col(N) = wn*64 + ni*16+lr
  const int which = n0 >> 11;          // 0:q 1:k 2:v
  const int bbid = m0 >> 11;
  const int s0 = m0 & 2047;
  if (which == 2) {
    // V transposed: [BH, Dh, S]; 4 regs = 4 consecutive s -> 8B store
#pragma unroll
    for (int ni = 0; ni < 4; ++ni) {
      const int ng = n0 + wn * 64 + ni * 16 + lr;
      const int h = (ng >> 7) & 15;
      const int d = ng & 127;
      const float bv = (float)bias[ng];
      bf16* rowp =
          outv + ((size_t)(bbid * NHEAD + h) * DHEAD + d) * SEQ + s0 + wm * 128;
#pragma unroll
      for (int ai = 0; ai < 8; ++ai) {
        bf16x4 pk;
#pragma unroll
        for (int reg = 0; reg < 4; ++reg)
          pk[reg] = (bf16)(acc[ai][ni][reg] + bv);
        *(bf16x4*)(rowp + ai * 16 + lq * 4) = pk;
      }
    }
  } else {
    bf16* dst = (which == 0) ? outq : outk;
#pragma unroll
    for (int ni = 0; ni < 4; ++ni) {
      const int ng = n0 + wn * 64 + ni * 16 + lr;
      const int h = (ng >> 7) & 15;
      const int d = ng & 127;
      const float bv = (float)bias[ng];
      bf16* hb = dst + (size_t)(bbid * NHEAD + h) * SEQ * DHEAD + d;
#pragma unroll
      for (int ai = 0; ai < 8; ++ai)
#pragma unroll
        for (int reg = 0; reg < 4; ++reg) {
          const int s = s0 + wm * 128 + ai * 16 + lq * 4 + reg;
          hb[(size_t)s * DHEAD] = (bf16)(acc[ai][ni][reg] + bv);
        }
    }
  }
}

// ---------------------------------------------------------------------------
// 4-phase pipelined NT GEMM (r4, proven): used for the out-projection.
// BM=128, BN=256, BK=64; 512 thr = 8 waves (2M x 4N), 64x64 out/wave.
// UNCHANGED (control for this round's experiments).
// ---------------------------------------------------------------------------
template <int MODE>
__global__ __launch_bounds__(512, 1) void gemmE(
    const bf16* __restrict__ A, const bf16* __restrict__ B,
    const bf16* __restrict__ bias, int K,
    void* __restrict__ out0v, bf16* __restrict__ out1, bf16* __restrict__ out2,
    const int* __restrict__ flagp)
{
  __shared__ __align__(16) bf16 lds_[49152];  // 96 KiB
  constexpr int NTX = (MODE == 0) ? 24 : 8;   // N / 256
  const int t = threadIdx.x;
  const int lane = t & 63, w = t >> 6;
  const int wm = w >> 2, wn = w & 3;          // 2M x 4N waves
  const int lr = lane & 15, lq = lane >> 4;
  const int nwg = 32 * NTX;
  const int f = blockIdx.x;
  const int o = (f & 7) * (nwg >> 3) + (f >> 3);
  const int by = o & 31, bx = o >> 5;
  const int m0 = by << 7, n0 = bx << 8;
  const int NT = K >> 6;                      // 32 K-tiles
  const int NI = NT >> 1;                     // 16 iterations

  const int srow = t >> 2;
  const int sg8 = (((t & 3) ^ (((t >> 5) & 1) << 1))) << 3;

#define STAGE3(kt_, ks_)                                                     \
  {                                                                          \
    const int _kt = (kt_), _ks = (ks_);                                      \
    if (_kt < NT) {                                                          \
      const int _bb = (_kt & 1) * 24576;                                     \
      const int _kc = (_kt << 6) + _ks * 32;                                 \
      llds16(lds_ + _bb + _ks * 4096 + (w << 9),                             \
             A + (size_t)(m0 + srow) * K + _kc + sg8);                       \
      llds16(lds_ + _bb + 8192 + _ks * 8192 + (w << 9),                      \
             B + (size_t)(n0 + srow) * K + _kc + sg8);                       \
      llds16(lds_ + _bb + 8192 + _ks * 8192 + 4096 + (w << 9),               \
             B + (size_t)(n0 + 128 + srow) * K + _kc + sg8);                 \
    }                                                                        \
  }

  f32x4 acc[4][4];
#pragma unroll
  for (int i = 0; i < 4; ++i)
#pragma unroll
    for (int j = 0; j < 4; ++j) acc[i][j] = (f32x4){0.f, 0.f, 0.f, 0.f};

  const int rg8 = ((lq ^ (((lr >> 3) & 1) << 1))) << 3;
  const int arow = (wm * 64 + lr) * 32 + rg8;
  const int brow = (wn * 64 + lr) * 32 + rg8;

  STAGE3(0, 0);
  STAGE3(0, 1);
  STAGE3(1, 0);
  asm volatile("s_waitcnt vmcnt(6)" ::: "memory");
  BARRAW();

  for (int i = 0; i < NI; ++i) {
    const int k2 = i << 1;
#pragma unroll
    for (int p = 0; p < 4; ++p) {
      const int ks = p & 1;
      const int bufb = (p >> 1) * 24576;
      bf16x8 af[4], bfv[4];
      const int ab = bufb + ks * 4096 + arow;
      const int bb = bufb + 8192 + ks * 8192 + brow;
#pragma unroll
      for (int mi = 0; mi < 4; ++mi)
        af[mi] = *(const bf16x8*)(lds_ + ab + mi * 512);
#pragma unroll
      for (int ni = 0; ni < 4; ++ni)
        bfv[ni] = *(const bf16x8*)(lds_ + bb + ni * 512);
      if (p == 0)      STAGE3(k2 + 1, 1)
      else if (p == 1) STAGE3(k2 + 2, 0)
      else if (p == 2) STAGE3(k2 + 2, 1)
      else             STAGE3(k2 + 3, 0)
      BARRAW();
      __builtin_amdgcn_s_setprio(1);
#pragma unroll
      for (int mi = 0; mi < 4; ++mi)
#pragma unroll
        for (int ni = 0; ni < 4; ++ni)
          acc[mi][ni] = mfma_16x16x32(af[mi], bfv[ni], acc[mi][ni]);
      __builtin_amdgcn_s_setprio(0);
      if (i == 0 && p == 0) {
        asm volatile("s_waitcnt vmcnt(6)" ::: "memory");
      }
      if (p == 1) {
        if (i == NI - 1) { asm volatile("s_waitcnt vmcnt(0)" ::: "memory"); }
        else             { asm volatile("s_waitcnt vmcnt(3)" ::: "memory"); }
      }
      if (p == 3 && i < NI - 1) {
        asm volatile("s_waitcnt vmcnt(3)" ::: "memory");
      }
      BARRAW();
    }
  }
#undef STAGE3

  if (MODE == 0) {
    const int which = n0 >> 11;
    const int bbid = m0 >> 11;
    const int s0 = m0 & 2047;
    if (which == 2) {
      bf16* dst = out2;
#pragma unroll
      for (int ni = 0; ni < 4; ++ni) {
        const int ng = n0 + wn * 64 + ni * 16 + lr;
        const int h = (ng >> 7) & 15;
        const int d = ng & 127;
        const float bv = (float)bias[ng];
        bf16* rowp =
            dst + ((size_t)(bbid * NHEAD + h) * DHEAD + d) * SEQ + s0 + wm * 64;
#pragma unroll
        for (int mi = 0; mi < 4; ++mi) {
          bf16x4 pk;
#pragma unroll
          for (int reg = 0; reg < 4; ++reg)
            pk[reg] = (bf16)(acc[mi][ni][reg] + bv);
          *(bf16x4*)(rowp + mi * 16 + lq * 4) = pk;
        }
      }
    } else {
      bf16* dst = (which == 0) ? (bf16*)out0v : out1;
#pragma unroll
      for (int ni = 0; ni < 4; ++ni) {
        const int ng = n0 + wn * 64 + ni * 16 + lr;
        const int h = (ng >> 7) & 15;
        const int d = ng & 127;
        const float bv = (float)bias[ng];
        bf16* hb = dst + (size_t)(bbid * NHEAD + h) * SEQ * DHEAD + d;
#pragma unroll
        for (int mi = 0; mi < 4; ++mi)
#pragma unroll
          for (int reg = 0; reg < 4; ++reg) {
            const int s = s0 + wm * 64 + mi * 16 + lq * 4 + reg;
            hb[(size_t)s * DHEAD] = (bf16)(acc[mi][ni][reg] + bv);
          }
      }
    }
  } else {
    const int isf32 = *flagp;
#pragma unroll
    for (int ni = 0; ni < 4; ++ni) {
      const int col = n0 + wn * 64 + ni * 16 + lr;
      const float bv = (float)bias[col];
#pragma unroll
      for (int mi = 0; mi < 4; ++mi)
#pragma unroll
        for (int reg = 0; reg < 4; ++reg) {
          const int row = m0 + wm * 64 + mi * 16 + lq * 4 + reg;
          const float v = acc[mi][ni][reg] + bv;
          const size_t idx = (size_t)row * EMBED + col;
          if (isf32) ((float*)out0v)[idx] = v;
          else       ((bf16*)out0v)[idx] = (bf16)v;
        }
    }
  }
}

// ---------------------------------------------------------------------------
// Causal flash attention, pair-balanced. r6: defer-max (T13), setprio around
// MFMA clusters (T5), bijective XCD swizzle (4 heads/XCD -> K/V L2-resident).
// ---------------------------------------------------------------------------
__device__ __forceinline__ void qk_softmax_tile(
    const bf16* __restrict__ sK, bf16* __restrict__ sP, const bf16x8* aq,
    float& m_i, float& l_i, f32x4* oacc, int kt, int qt,
    int w, int lr, int lq, int sPofs)
{
  const float scale = 0.08838834764831845f;  // 1/sqrt(128)
  f32x4 tacc[4];
#pragma unroll
  for (int ni = 0; ni < 4; ++ni) tacc[ni] = (f32x4){0.f, 0.f, 0.f, 0.f};
  __builtin_amdgcn_s_setprio(1);
#pragma unroll
  for (int ks = 0; ks < 4; ++ks)
#pragma unroll
    for (int ni = 0; ni < 4; ++ni) {
      bf16x8 bk = *(const bf16x8*)(sK + (ni * 16 + lr) * 136 + ks * 32 + lq * 8);
      tacc[ni] = mfma_16x16x32(bk, aq[ks], tacc[ni]);
    }
  __builtin_amdgcn_s_setprio(0);
  float pp[4][4];
  const int qg = qt * 64 + w * 16 + lr;
#pragma unroll
  for (int ni = 0; ni < 4; ++ni)
#pragma unroll
    for (int reg = 0; reg < 4; ++reg) {
      float sv = tacc[ni][reg] * scale;
      if (kt == qt) {
        const int kg = kt * 64 + ni * 16 + lq * 4 + reg;
        if (kg > qg) sv = NEG_BIG;
      }
      pp[ni][reg] = sv;
    }
  float mx;
  {
    float a0 = fmaxf(fmaxf(pp[0][0], pp[0][1]), fmaxf(pp[0][2], pp[0][3]));
    float a1 = fmaxf(fmaxf(pp[1][0], pp[1][1]), fmaxf(pp[1][2], pp[1][3]));
    float a2 = fmaxf(fmaxf(pp[2][0], pp[2][1]), fmaxf(pp[2][2], pp[2][3]));
    float a3 = fmaxf(fmaxf(pp[3][0], pp[3][1]), fmaxf(pp[3][2], pp[3][3]));
    mx = fmaxf(fmaxf(a0, a1), fmaxf(a2, a3));
  }
  mx = fmaxf(mx, __shfl_xor(mx, 16, 64));
  mx = fmaxf(mx, __shfl_xor(mx, 32, 64));
  // defer-max (T13): skip the O/l rescale while the running max grows < 8.
  // P is then bounded by e^8 (bf16/f32 accum headroom fine); first tile
  // always takes the branch (m_i = NEG_BIG).
  if (!__all(mx <= m_i + 8.0f)) {
    const float mnew = fmaxf(m_i, mx);
    const float alpha = __expf(m_i - mnew);
    l_i *= alpha;
#pragma unroll
    for (int dt = 0; dt < 8; ++dt) oacc[dt] *= alpha;
    m_i = mnew;
  }
  float ls = 0.f;
#pragma unroll
  for (int ni = 0; ni < 4; ++ni) {
    float s0 = __expf(pp[ni][0] - m_i);
    float s1 = __expf(pp[ni][1] - m_i);
    float s2 = __expf(pp[ni][2] - m_i);
    float s3 = __expf(pp[ni][3] - m_i);
    pp[ni][0] = s0; pp[ni][1] = s1; pp[ni][2] = s2; pp[ni][3] = s3;
    ls += (s0 + s1) + (s2 + s3);
  }
  ls += __shfl_xor(ls, 16, 64);
  ls += __shfl_xor(ls, 32, 64);
  l_i += ls;
  bf16* rowp = sP + (sPofs + w * 16 + lr) * 64;
  const int swz = lr & 7;
#pragma unroll
  for (int ni = 0; ni < 4; ++ni) {
    bf16x4 pk;
#pragma unroll
    for (int reg = 0; reg < 4; ++reg) pk[reg] = (bf16)pp[ni][reg];
    const int col = ni * 16 + lq * 4;
    const int scol = (((col >> 3) ^ swz) << 3) | (col & 7);
    *(bf16x4*)(rowp + scol) = pk;
  }
}

__device__ __forceinline__ void pv_tile(const bf16* __restrict__ sP,
                                        const bf16* __restrict__ sV,
                                        f32x4* oacc, int w, int lr, int lq,
                                        int sPofs)
{
  const bf16* rowp = sP + (sPofs + w * 16 + lr) * 64;
  const int swz = lr & 7;
  __builtin_amdgcn_s_setprio(1);
#pragma unroll
  for (int ks2 = 0; ks2 < 2; ++ks2) {
    const int chunk = ks2 * 4 + lq;
    bf16x8 bp = *(const bf16x8*)(rowp + ((chunk ^ swz) << 3));
#pragma unroll
    for (int dt = 0; dt < 8; ++dt) {
      bf16x8 av =
          *(const bf16x8*)(sV + (dt * 16 + lr) * 72 + ks2 * 32 + lq * 8);
      oacc[dt] = mfma_16x16x32(av, bp, oacc[dt]);
    }
  }
  __builtin_amdgcn_s_setprio(0);
}

__global__ __launch_bounds__(256, 2) void attn_fwd(
    const bf16* __restrict__ qb, const bf16* __restrict__ kb,
    const bf16* __restrict__ vt, bf16* __restrict__ aout)
{
  __shared__ bf16 sK[64 * 136];    // [k][d], +8 pad
  __shared__ bf16 sV[128 * 72];    // [d][k], +8 pad
  __shared__ bf16 sP[128 * 64];    // [q][k] XOR-swizzled
  const int t = threadIdx.x;
  const int lane = t & 63, w = t >> 6;
  const int lr = lane & 15, lq = lane >> 4;
  // XCD-bijective swizzle: 512 = 8 * 64; each XCD gets 4 consecutive heads
  // (16 p-blocks each) -> that XCD's L2 holds their K/V (4 x ~1MB).
  const int f = blockIdx.x;
  const int o = (f & 7) * 64 + (f >> 3);
  const int p  = o & 15;
  const int bh = o >> 4;
  const int bb = bh >> 4, h = bh & 15;
  const int qlo = p, qhi = 31 - p;

  bf16x8 aqL[4], aqH[4];
  {
    const bf16* qpL =
        qb + ((size_t)bh * SEQ + qlo * 64 + w * 16 + lr) * DHEAD + lq * 8;
    const bf16* qpH =
        qb + ((size_t)bh * SEQ + qhi * 64 + w * 16 + lr) * DHEAD + lq * 8;
#pragma unroll
    for (int ks = 0; ks < 4; ++ks) {
      aqL[ks] = *(const bf16x8*)(qpL + ks * 32);
      aqH[ks] = *(const bf16x8*)(qpH + ks * 32);
    }
  }

  f32x4 oL[8], oH[8];
#pragma unroll
  for (int i = 0; i < 8; ++i) {
    oL[i] = (f32x4){0.f, 0.f, 0.f, 0.f};
    oH[i] = (f32x4){0.f, 0.f, 0.f, 0.f};
  }
  float mL = NEG_BIG, mH = NEG_BIG;
  float lL = 0.f, lH = 0.f;

  bf16x8 rk[4], rv[4];
  const int kr_ = t >> 4, kd_ = t & 15;
  const int vr_ = t >> 3, vk_ = t & 7;
#define FETCH(ktv)                                                          \
  {                                                                         \
    const int _kt = (ktv);                                                  \
    _Pragma("unroll") for (int i = 0; i < 4; ++i) {                         \
      rk[i] = *(const bf16x8*)(kb + ((size_t)bh * SEQ + _kt * 64 +          \
                                     (i * 16 + kr_)) * DHEAD + kd_ * 8);    \
      rv[i] = *(const bf16x8*)(vt + ((size_t)bh * DHEAD + (i * 32 + vr_)) * \
                                     SEQ + _kt * 64 + vk_ * 8);             \
    }                                                                       \
  }
#define COMMIT()                                                            \
  {                                                                         \
    _Pragma("unroll") for (int i = 0; i < 4; ++i) {                         \
      *(bf16x8*)(sK + (i * 16 + kr_) * 136 + kd_ * 8) = rk[i];              \
      *(bf16x8*)(sV + (i * 32 + vr_) * 72 + vk_ * 8) = rv[i];               \
    }                                                                       \
  }

  FETCH(0);
  COMMIT();
  __syncthreads();

  for (int kt = 0; kt <= qhi; ++kt) {
    if (kt < qhi) FETCH(kt + 1);
    const bool doLo = (kt <= qlo);

    qk_softmax_tile(sK, sP, aqH, mH, lH, oH, kt, qhi, w, lr, lq, 64);
    if (doLo) qk_softmax_tile(sK, sP, aqL, mL, lL, oL, kt, qlo, w, lr, lq, 0);
    asm volatile("s_waitcnt lgkmcnt(0)" ::: "memory");
    pv_tile(sP, sV, oH, w, lr, lq, 64);
    if (doLo) pv_tile(sP, sV, oL, w, lr, lq, 0);

    __syncthreads();
    if (kt < qhi) {
      COMMIT();
      __syncthreads();
    }
  }

#pragma unroll
  for (int side = 0; side < 2; ++side) {
    const f32x4* oacc = side ? oH : oL;
    const float linv = 1.0f / (side ? lH : lL);
    const int qt = side ? qhi : qlo;
    const int qg = qt * 64 + w * 16 + lr;
    bf16* outp = aout + ((size_t)bb * SEQ + qg) * EMBED + h * 128 + lq * 4;
#pragma unroll
    for (int dt = 0; dt < 8; ++dt) {
      bf16x4 pk;
#pragma unroll
      for (int reg = 0; reg < 4; ++reg)
        pk[reg] = (bf16)(oacc[dt][reg] * linv);
      *(bf16x4*)(outp + dt * 16) = pk;
    }
  }
#undef FETCH
#undef COMMIT
}

extern "C" void kernel_launch(void* const* d_in, const int* in_sizes, int n_in,
                              void* d_out, int out_size, void* d_ws, size_t ws_size,
                              hipStream_t stream) {
  const void* x    = d_in[0];
  const void* Wqkv = d_in[1];
  const void* bqkv = d_in[2];
  const void* Wout = d_in[3];
  const void* bout = d_in[4];

  int* flagp = (int*)d_ws;
  bf16* base = (bf16*)((char*)d_ws + 256);
  bf16* xb   = base;
  bf16* w1b  = xb + NX;
  bf16* b1b  = w1b + NW1;
  bf16* w2b  = b1b + NB1;
  bf16* b2b  = w2b + NW2;
  bf16* qb   = b2b + NB2;
  bf16* kb   = qb + NX;
  bf16* vt   = kb + NX;
  bf16* aout = vt + NX;

  convert_inputs<<<dim3(1024), dim3(256), 0, stream>>>(
      x, Wqkv, bqkv, Wout, bout, xb, w1b, b1b, w2b, b2b, flagp);
  // QKV projection: M=4096, N=6144, K=2048 -> 384 blocks of 256x256
  gemmM<<<dim3(384), dim3(512), 0, stream>>>(xb, w1b, b1b, qb, kb, vt);
  // attention: 32 bh * 16 balanced pairs
  attn_fwd<<<dim3(512), dim3(256), 0, stream>>>(qb, kb, vt, aout);
  // out projection: M=4096, N=2048, K=2048 -> 256 blocks = 1 exact round
  gemmE<1><<<dim3(256), dim3(512), 0, stream>>>(
      aout, w2b, b2b, EMBED, d_out, nullptr, nullptr, flagp);
}